// Round 16
// baseline (568.064 us; speedup 1.0000x reference)
//
#include <hip/hip_runtime.h>
#include <cstdint>

#define N_NODES 50000
#define N_EDGES 1600000
#define HDIM 128
#define L_LAYERS 4
#define BN_EPS 1e-5f
#define NPART 196
#define PART_SHIFT 8
#define PB_CHUNK 6250  // N_EDGES / 256 exactly
#define FP_CAP 16384
#define FL_RB 128

typedef __attribute__((ext_vector_type(8))) short short8v;
typedef __attribute__((ext_vector_type(4))) float f32x4;

__device__ __forceinline__ unsigned short f2bf(float f) {
    uint32_t u = __builtin_bit_cast(uint32_t, f);
    u += 0x7fff + ((u >> 16) & 1);
    return (unsigned short)(u >> 16);
}
__device__ __forceinline__ float bf2f(unsigned short b) {
    return __builtin_bit_cast(float, (uint32_t)b << 16);
}

__device__ __forceinline__ int read_mask(const void* mask, int i, int bytelayout) {
    if (bytelayout) return ((const unsigned char*)mask)[i] != 0;
    return ((const int*)mask)[i] != 0;
}

// ---------------- K1: mask-layout detect (block 256) + per-partition count ----
__global__ __launch_bounds__(256) void detect_pcount_kernel(const uint32_t* __restrict__ mw,
                                                            int* __restrict__ flag,
                                                            const int* __restrict__ dst,
                                                            int* __restrict__ pcount) {
    if (blockIdx.x == 256) {
        __shared__ int f;
        if (threadIdx.x == 0) f = 0;
        __syncthreads();
        int found = 0;
        for (int i = threadIdx.x; i < 12500; i += 256)
            if (mw[i] > 1u) found = 1;
        if (found) f = 1;
        __syncthreads();
        if (threadIdx.x == 0) *flag = f;
        return;
    }
    __shared__ int hist[NPART];
    for (int i = threadIdx.x; i < NPART; i += 256) hist[i] = 0;
    __syncthreads();
    int lo = blockIdx.x * PB_CHUNK;
    for (int i = threadIdx.x; i < PB_CHUNK; i += 256)
        atomicAdd(&hist[dst[lo + i] >> PART_SHIFT], 1);
    __syncthreads();
    for (int i = threadIdx.x; i < NPART; i += 256)
        if (hist[i]) atomicAdd(&pcount[i], hist[i]);
}

// ---------------- K2: weight prep (blocks 0..287) + embed (rest) ----------------
__global__ __launch_bounds__(256) void wprep_embed_kernel(
    const float* __restrict__ W1, const float* __restrict__ W2, const float* __restrict__ dW1,
    unsigned short* __restrict__ Wt1, unsigned short* __restrict__ Wt2,
    unsigned short* __restrict__ Wtd, const float* __restrict__ x, const void* __restrict__ mask,
    const int* __restrict__ flag, const float* __restrict__ tok, const float* __restrict__ eW,
    const float* __restrict__ eb, unsigned short* __restrict__ h) {
    if (blockIdx.x < 288) {
        int seg = blockIdx.x / 32, bx = blockIdx.x & 31;
        const float* W;
        unsigned short* Wt;
        int K, nshift;
        if (seg < 4) {
            W = W1 + (size_t)seg * HDIM * 2 * HDIM;
            Wt = Wt1 + (size_t)seg * HDIM * 2 * HDIM;
            K = HDIM;
            nshift = 8;
        } else if (seg < 8) {
            int l = seg - 4;
            W = W2 + (size_t)l * 2 * HDIM * HDIM;
            Wt = Wt2 + (size_t)l * 2 * HDIM * HDIM;
            K = 2 * HDIM;
            nshift = 7;
        } else {
            W = dW1;
            Wt = Wtd;
            K = HDIM;
            nshift = 7;
        }
        int total = K << nshift;
        for (int idx = bx * 256 + (int)threadIdx.x; idx < total; idx += 32 * 256) {
            int k = idx >> nshift, n = idx & ((1 << nshift) - 1);
            Wt[(size_t)n * K + k] = f2bf(W[idx]);
        }
        return;
    }
    int idx = (blockIdx.x - 288) * 256 + threadIdx.x;
    if (idx >= N_NODES * HDIM) return;
    int i = idx >> 7, c = idx & 127;
    int fl = *flag;
    int m = read_mask(mask, i, fl);
    float x0 = m ? tok[0] : x[i * 3 + 0];
    float x1 = m ? tok[1] : x[i * 3 + 1];
    float x2 = m ? tok[2] : x[i * 3 + 2];
    h[idx] = f2bf(x0 * eW[c] + x1 * eW[HDIM + c] + x2 * eW[2 * HDIM + c] + eb[c]);
}

// ---------------- CSR build ----------------
__global__ __launch_bounds__(256) void pscan_kernel(const int* __restrict__ pcount,
                                                    int* __restrict__ poff,
                                                    int* __restrict__ pcursor,
                                                    int* __restrict__ rowptr) {
    __shared__ int sh[256];
    int t = threadIdx.x;
    int v = (t < NPART) ? pcount[t] : 0;
    sh[t] = v;
    __syncthreads();
    for (int o = 1; o < 256; o <<= 1) {
        int u = (t >= o) ? sh[t - o] : 0;
        __syncthreads();
        sh[t] += u;
        __syncthreads();
    }
    if (t < NPART) {
        int e = sh[t] - v;
        poff[t] = e;
        pcursor[t] = e;
    }
    if (t == NPART - 1) {
        poff[NPART] = sh[t];
        rowptr[N_NODES] = sh[t];
    }
}

__global__ __launch_bounds__(256) void partition_kernel(const int* __restrict__ src,
                                                        const int* __restrict__ dst,
                                                        int* __restrict__ pcursor,
                                                        uint32_t* __restrict__ pairs) {
    __shared__ int hist[NPART];
    __shared__ int off[NPART];
    int b = blockIdx.x, t = threadIdx.x;
    int lo = b * PB_CHUNK;
    for (int i = t; i < NPART; i += 256) hist[i] = 0;
    __syncthreads();
    for (int i = t; i < PB_CHUNK; i += 256) {
        int d = dst[lo + i];
        atomicAdd(&hist[d >> PART_SHIFT], 1);
    }
    __syncthreads();
    for (int i = t; i < NPART; i += 256) off[i] = atomicAdd(&pcursor[i], hist[i]);
    __syncthreads();
    for (int i = t; i < PB_CHUNK; i += 256) {
        int d = dst[lo + i];
        int s = src[lo + i];
        int pos = atomicAdd(&off[d >> PART_SHIFT], 1);
        pairs[pos] = (uint32_t)s | ((uint32_t)(d & 255) << 16);
    }
}

__global__ __launch_bounds__(256) void fill_part_kernel(const uint32_t* __restrict__ pairs,
                                                        const int* __restrict__ poff,
                                                        int* __restrict__ rowptr,
                                                        int* __restrict__ col) {
    __shared__ int colw[FP_CAP];
    __shared__ int lscan[256];
    __shared__ int lcur[256];
    int p = blockIdx.x, t = threadIdx.x;
    int base = p << PART_SHIFT;
    int nlocal = min(256, N_NODES - base);
    int pstart = poff[p], pend = poff[p + 1];
    int cnt = pend - pstart;
    lcur[t] = 0;
    __syncthreads();
    for (int e = pstart + t; e < pend; e += 256)
        atomicAdd(&lcur[(__builtin_nontemporal_load(&pairs[e]) >> 16) & 255], 1);
    __syncthreads();
    int v = lcur[t];
    lscan[t] = v;
    __syncthreads();
    for (int o = 1; o < 256; o <<= 1) {
        int u = (t >= o) ? lscan[t - o] : 0;
        __syncthreads();
        lscan[t] += u;
        __syncthreads();
    }
    int excl = lscan[t] - v;
    if (t < nlocal) rowptr[base + t] = pstart + excl;
    lcur[t] = excl;
    __syncthreads();
    if (cnt <= FP_CAP) {
        for (int e = pstart + t; e < pend; e += 256) {
            uint32_t pv = pairs[e];
            int pos = atomicAdd(&lcur[(pv >> 16) & 255], 1);
            colw[pos] = (int)(pv & 0xFFFFu);
        }
        __syncthreads();
        for (int e = t; e < cnt; e += 256) col[pstart + e] = colw[e];
    } else {
        for (int e = pstart + t; e < pend; e += 256) {
            uint32_t pv = pairs[e];
            int pos = atomicAdd(&lcur[(pv >> 16) & 255], 1);
            col[pstart + pos] = (int)(pv & 0xFFFFu);
        }
    }
}

// ---------------- aggregation (bf16 h): z[i] = h[i] + sum_{j} h[j] ----------------
#define AGG_LD(k)                                               \
    {                                                           \
        uint32_t uu = h32[(size_t)j##k * 64 + lane];            \
        ac##k.x += __builtin_bit_cast(float, uu << 16);         \
        ac##k.y += __builtin_bit_cast(float, uu & 0xffff0000u); \
    }
__global__ __launch_bounds__(256) void agg_kernel(const unsigned short* __restrict__ h,
                                                  const int* __restrict__ rowptr,
                                                  const int* __restrict__ col,
                                                  unsigned short* __restrict__ z) {
    int wid = threadIdx.x >> 6;
    int lane = threadIdx.x & 63;
    int i = __builtin_amdgcn_readfirstlane(blockIdx.x * 4 + wid);
    if (i >= N_NODES) return;
    int start = rowptr[i], end = rowptr[i + 1];
    const uint32_t* h32 = (const uint32_t*)h;
    uint32_t u = h32[(size_t)i * 64 + lane];
    float2 ac0 = make_float2(__builtin_bit_cast(float, u << 16),
                             __builtin_bit_cast(float, u & 0xffff0000u));
    float2 ac1 = make_float2(0.f, 0.f), ac2 = make_float2(0.f, 0.f), ac3 = make_float2(0.f, 0.f);
    float2 ac4 = make_float2(0.f, 0.f), ac5 = make_float2(0.f, 0.f), ac6 = make_float2(0.f, 0.f);
    float2 ac7 = make_float2(0.f, 0.f), ac8 = make_float2(0.f, 0.f), ac9 = make_float2(0.f, 0.f);
    float2 ac10 = make_float2(0.f, 0.f), ac11 = make_float2(0.f, 0.f),
           ac12 = make_float2(0.f, 0.f);
    float2 ac13 = make_float2(0.f, 0.f), ac14 = make_float2(0.f, 0.f),
           ac15 = make_float2(0.f, 0.f);
    int e = start;
    for (; e + 16 <= end; e += 16) {
        int j0 = col[e + 0], j1 = col[e + 1], j2 = col[e + 2], j3 = col[e + 3];
        int j4 = col[e + 4], j5 = col[e + 5], j6 = col[e + 6], j7 = col[e + 7];
        int j8 = col[e + 8], j9 = col[e + 9], j10 = col[e + 10], j11 = col[e + 11];
        int j12 = col[e + 12], j13 = col[e + 13], j14 = col[e + 14], j15 = col[e + 15];
        AGG_LD(0) AGG_LD(1) AGG_LD(2) AGG_LD(3) AGG_LD(4) AGG_LD(5) AGG_LD(6) AGG_LD(7)
        AGG_LD(8) AGG_LD(9) AGG_LD(10) AGG_LD(11) AGG_LD(12) AGG_LD(13) AGG_LD(14) AGG_LD(15)
    }
    for (; e + 4 <= end; e += 4) {
        int j0 = col[e + 0], j1 = col[e + 1], j2 = col[e + 2], j3 = col[e + 3];
        AGG_LD(0) AGG_LD(1) AGG_LD(2) AGG_LD(3)
    }
    for (; e < end; ++e) {
        int j0 = col[e];
        AGG_LD(0)
    }
    ac0.x += ((ac1.x + ac2.x) + (ac3.x + ac4.x)) + ((ac5.x + ac6.x) + (ac7.x + ac8.x)) +
             ((ac9.x + ac10.x) + (ac11.x + ac12.x)) + ((ac13.x + ac14.x) + ac15.x);
    ac0.y += ((ac1.y + ac2.y) + (ac3.y + ac4.y)) + ((ac5.y + ac6.y) + (ac7.y + ac8.y)) +
             ((ac9.y + ac10.y) + (ac11.y + ac12.y)) + ((ac13.y + ac14.y) + ac15.y);
    uint32_t o = (uint32_t)f2bf(ac0.x) | ((uint32_t)f2bf(ac0.y) << 16);
    ((uint32_t*)z)[(size_t)i * 64 + lane] = o;
}

// ---------------- fused layer (weight-stationary LDS); zin out = bf16 ----------------
// BN stats computed from the ROUNDED values so normalization is self-consistent.
__global__ __launch_bounds__(512) void fused_layer_kernel(
    const unsigned short* __restrict__ z, const unsigned short* __restrict__ Wt1,
    const float* __restrict__ b1, const unsigned short* __restrict__ Wt2,
    const float* __restrict__ b2, unsigned short* __restrict__ zin, float* __restrict__ stats,
    int M) {
    __shared__ unsigned short wbuf[256 * 136];
    __shared__ unsigned short z1l[FL_RB * 264];
    const int t = threadIdx.x;
    const int lane = t & 63;
    const int w = t >> 6;
    const int r = lane & 15, ks = lane >> 4;
    const int row0 = blockIdx.x * FL_RB + w * 16;
    const int arow = min(row0 + r, M - 1);
    for (int i = t; i < 256 * 16; i += 512) {
        int row = i >> 4, seg = i & 15;
        *(short8v*)&wbuf[row * 136 + seg * 8] = *(const short8v*)&Wt1[(size_t)row * 128 + seg * 8];
    }
    short8v a4[4];
#pragma unroll
    for (int kk = 0; kk < 4; ++kk)
        a4[kk] = *(const short8v*)&z[(size_t)arow * HDIM + kk * 32 + ks * 8];
    __syncthreads();
#pragma unroll
    for (int n = 0; n < 16; ++n) {
        f32x4 acc = (f32x4){0.f, 0.f, 0.f, 0.f};
#pragma unroll
        for (int kk = 0; kk < 4; ++kk) {
            short8v bf = *(const short8v*)&wbuf[(n * 16 + r) * 136 + kk * 32 + ks * 8];
            acc = __builtin_amdgcn_mfma_f32_16x16x32_bf16(a4[kk], bf, acc, 0, 0, 0);
        }
        float bv = b1[n * 16 + r];
#pragma unroll
        for (int i = 0; i < 4; ++i) {
            float o = fmaxf(acc[i] + bv, 0.f);
            z1l[(w * 16 + ks * 4 + i) * 264 + n * 16 + r] = f2bf(o);
        }
    }
    __syncthreads();
    for (int i = t; i < 128 * 32; i += 512) {
        int row = i >> 5, seg = i & 31;
        *(short8v*)&wbuf[row * 264 + seg * 8] = *(const short8v*)&Wt2[(size_t)row * 256 + seg * 8];
    }
    __syncthreads();
    f32x4 accb[8];
#pragma unroll
    for (int n = 0; n < 8; ++n) accb[n] = (f32x4){0.f, 0.f, 0.f, 0.f};
#pragma unroll
    for (int k0 = 0; k0 < 256; k0 += 32) {
        short8v a = *(const short8v*)&z1l[(w * 16 + r) * 264 + k0 + ks * 8];
#pragma unroll
        for (int n = 0; n < 8; ++n) {
            short8v bf = *(const short8v*)&wbuf[(n * 16 + r) * 264 + k0 + ks * 8];
            accb[n] = __builtin_amdgcn_mfma_f32_16x16x32_bf16(a, bf, accb[n], 0, 0, 0);
        }
    }
    __syncthreads();
    float* sred = (float*)wbuf;
#pragma unroll
    for (int n = 0; n < 8; ++n) {
        const int cc = n * 16 + r;
        const float bv = b2[cc];
        float s = 0.f, ss = 0.f;
#pragma unroll
        for (int i = 0; i < 4; ++i) {
            int row = row0 + ks * 4 + i;
            if (row < M) {
                float o = accb[n][i] + bv;
                unsigned short ur = f2bf(o);
                float orf = bf2f(ur);
                s += orf;
                ss += orf * orf;
                zin[(size_t)row * HDIM + cc] = ur;
            }
        }
        s += __shfl_xor(s, 16);
        s += __shfl_xor(s, 32);
        ss += __shfl_xor(ss, 16);
        ss += __shfl_xor(ss, 32);
        if (ks == 0) {
            sred[(w * 2 + 0) * HDIM + cc] = s;
            sred[(w * 2 + 1) * HDIM + cc] = ss;
        }
    }
    __syncthreads();
    if (t < HDIM) {
        float s = 0.f, ss = 0.f;
#pragma unroll
        for (int ww = 0; ww < 8; ++ww) {
            s += sred[(ww * 2 + 0) * HDIM + t];
            ss += sred[(ww * 2 + 1) * HDIM + t];
        }
        atomicAdd(&stats[t], s);
        atomicAdd(&stats[HDIM + t], ss);
    }
}

// ---------------- BN apply (bf16 in, bf16 out, 8 elems/thread) ----------------
__global__ __launch_bounds__(256) void bnapply_kernel(const unsigned short* __restrict__ zin,
                                                      const float* __restrict__ stats,
                                                      const float* __restrict__ gamma,
                                                      const float* __restrict__ beta,
                                                      unsigned short* __restrict__ h) {
    __shared__ float ssc[2 * HDIM];
    int t = threadIdx.x;
    if (t < HDIM) {
        float mean = stats[t] * (1.f / N_NODES);
        float var = stats[HDIM + t] * (1.f / N_NODES) - mean * mean;
        float rstd = rsqrtf(fmaxf(var, 0.f) + BN_EPS);
        float s = gamma[t] * rstd;
        ssc[t] = s;
        ssc[HDIM + t] = beta[t] - mean * s;
    }
    __syncthreads();
    int idx = blockIdx.x * 256 + t;
    if (idx >= N_NODES * HDIM / 8) return;
    short8v v = ((const short8v*)zin)[idx];
    int c = (idx * 8) & 127;
    short8v o;
#pragma unroll
    for (int j = 0; j < 8; ++j) {
        float val = fmaxf(bf2f((unsigned short)v[j]) * ssc[c + j] + ssc[HDIM + c + j], 0.f);
        o[j] = (short)f2bf(val);
    }
    ((short8v*)h)[idx] = o;
}

// ---------------- fused decoder: d1 = relu(h@Wd1+db1) [MFMA->LDS]; recon+loss ----------------
__global__ __launch_bounds__(512) void dec_fused_kernel(
    const unsigned short* __restrict__ h, const unsigned short* __restrict__ Wtd,
    const float* __restrict__ db1, const float* __restrict__ dW2, const float* __restrict__ db2,
    const float* __restrict__ x, const void* __restrict__ mask, const int* __restrict__ flag,
    float* __restrict__ recon, float* __restrict__ acc, int* __restrict__ cnt,
    float* __restrict__ out_loss, int nblocks) {
    __shared__ unsigned short d1l[64 * 136];
    __shared__ float w2s[HDIM * 3];
    const int t = threadIdx.x;
    for (int i = t; i < HDIM * 3; i += 512) w2s[i] = dW2[i];
    const int lane = t & 63;
    const int w = t >> 6;
    const int r = lane & 15, ks = lane >> 4;
    const int row0 = blockIdx.x * 64 + (w & 3) * 16;
    const int col0 = (w >> 2) * 64;
    const int arow = min(row0 + r, N_NODES - 1);
    f32x4 accd[4];
#pragma unroll
    for (int n = 0; n < 4; ++n) accd[n] = (f32x4){0.f, 0.f, 0.f, 0.f};
#pragma unroll
    for (int k0 = 0; k0 < HDIM; k0 += 32) {
        short8v a = *(const short8v*)&h[(size_t)arow * HDIM + k0 + ks * 8];
#pragma unroll
        for (int n = 0; n < 4; ++n) {
            short8v b = *(const short8v*)&Wtd[(size_t)(col0 + n * 16 + r) * HDIM + k0 + ks * 8];
            accd[n] = __builtin_amdgcn_mfma_f32_16x16x32_bf16(a, b, accd[n], 0, 0, 0);
        }
    }
#pragma unroll
    for (int n = 0; n < 4; ++n) {
        const int col = col0 + n * 16 + r;
        const float bv = db1[col];
#pragma unroll
        for (int i = 0; i < 4; ++i) {
            int lrow = (w & 3) * 16 + ks * 4 + i;
            d1l[lrow * 136 + col] = f2bf(fmaxf(accd[n][i] + bv, 0.f));
        }
    }
    __syncthreads();
    // dec2: 8 threads per node
    int lrow = t >> 3, q = t & 7;
    int node = blockIdx.x * 64 + lrow;
    int fl = *flag;
    float lsum = 0.f, lcnt = 0.f;
    float s0 = 0.f, s1 = 0.f, s2 = 0.f;
    if (node < N_NODES) {
        short8v v0 = *(const short8v*)&d1l[lrow * 136 + q * 16];
        short8v v1 = *(const short8v*)&d1l[lrow * 136 + q * 16 + 8];
#pragma unroll
        for (int j = 0; j < 8; ++j) {
            float a0 = bf2f((unsigned short)v0[j]);
            int c0 = q * 16 + j;
            s0 = fmaf(a0, w2s[c0 * 3 + 0], s0);
            s1 = fmaf(a0, w2s[c0 * 3 + 1], s1);
            s2 = fmaf(a0, w2s[c0 * 3 + 2], s2);
            float a1 = bf2f((unsigned short)v1[j]);
            int c1 = c0 + 8;
            s0 = fmaf(a1, w2s[c1 * 3 + 0], s0);
            s1 = fmaf(a1, w2s[c1 * 3 + 1], s1);
            s2 = fmaf(a1, w2s[c1 * 3 + 2], s2);
        }
    }
#pragma unroll
    for (int o = 1; o <= 4; o <<= 1) {
        s0 += __shfl_xor(s0, o);
        s1 += __shfl_xor(s1, o);
        s2 += __shfl_xor(s2, o);
    }
    if (node < N_NODES && q == 0) {
        float r0 = s0 + db2[0], r1 = s1 + db2[1], r2 = s2 + db2[2];
        recon[(size_t)node * 3 + 0] = r0;
        recon[(size_t)node * 3 + 1] = r1;
        recon[(size_t)node * 3 + 2] = r2;
        if (read_mask(mask, node, fl)) {
            float rn = fmaxf(sqrtf(r0 * r0 + r1 * r1 + r2 * r2), 1e-12f);
            float x0 = x[node * 3 + 0], x1 = x[node * 3 + 1], x2 = x[node * 3 + 2];
            float xn = fmaxf(sqrtf(x0 * x0 + x1 * x1 + x2 * x2), 1e-12f);
            float cs = (r0 * x0 + r1 * x1 + r2 * x2) / (rn * xn);
            float d = 1.f - cs;
            lsum = d * d;
            lcnt = 1.f;
        }
    }
#pragma unroll
    for (int o = 8; o <= 32; o <<= 1) {
        lsum += __shfl_xor(lsum, o);
        lcnt += __shfl_xor(lcnt, o);
    }
    if (lane == 0 && lcnt != 0.f) {
        atomicAdd(&acc[0], lsum);
        atomicAdd(&acc[1], lcnt);
    }
    __syncthreads();
    if (t == 0) {
        __threadfence();
        int done = atomicAdd(cnt, 1);
        if (done == nblocks - 1) {
            __threadfence();
            out_loss[0] = acc[0] / fmaxf(acc[1], 1.f);
        }
    }
}

// ---------------- launcher ----------------
extern "C" void kernel_launch(void* const* d_in, const int* in_sizes, int n_in, void* d_out,
                              int out_size, void* d_ws, size_t ws_size, hipStream_t stream) {
    const float* x = (const float*)d_in[0];
    const int* ei = (const int*)d_in[1];
    const int* src = ei;
    const int* dst = ei + N_EDGES;
    const void* mask = d_in[3];
    const float* tok = (const float*)d_in[4];
    const float* eW = (const float*)d_in[5];
    const float* eb = (const float*)d_in[6];
    const float* W1 = (const float*)d_in[7];
    const float* b1 = (const float*)d_in[8];
    const float* W2 = (const float*)d_in[9];
    const float* b2 = (const float*)d_in[10];
    const float* gm = (const float*)d_in[11];
    const float* bt = (const float*)d_in[12];
    const float* dW1 = (const float*)d_in[13];
    const float* db1 = (const float*)d_in[14];
    const float* dW2 = (const float*)d_in[15];
    const float* db2 = (const float*)d_in[16];
    float* out = (float*)d_out;

    char* ws = (char*)d_ws;
    size_t off = 0;
    auto alloc = [&](size_t bytes) -> void* {
        void* p = ws + off;
        off = (off + bytes + 255) & ~(size_t)255;
        return p;
    };
    unsigned short* h = (unsigned short*)alloc((size_t)N_NODES * HDIM * 2);
    unsigned short* z = (unsigned short*)alloc((size_t)N_NODES * HDIM * 2);
    unsigned short* zin = (unsigned short*)alloc((size_t)N_NODES * HDIM * 2);
    unsigned short* Wt1 = (unsigned short*)alloc((size_t)L_LAYERS * HDIM * 2 * HDIM * 2);
    unsigned short* Wt2 = (unsigned short*)alloc((size_t)L_LAYERS * HDIM * 2 * HDIM * 2);
    unsigned short* Wtd = (unsigned short*)alloc((size_t)HDIM * HDIM * 2);
    int* rowptr = (int*)alloc((size_t)(N_NODES + 1) * 4);
    int* col = (int*)alloc((size_t)N_EDGES * 4);
    uint32_t* pairs = (uint32_t*)alloc((size_t)N_EDGES * 4);
    int* poff = (int*)alloc((size_t)(NPART + 1) * 4);
    int* pcursor = (int*)alloc((size_t)NPART * 4);
    int* flag = (int*)alloc(4);
    // zero-region (single memset): pcount, stats, lacc, cnt
    char* zr0 = ws + off;
    int* pcount = (int*)alloc((size_t)NPART * 4);
    float* stats = (float*)alloc((size_t)L_LAYERS * 2 * HDIM * 4);
    float* lacc = (float*)alloc(8);
    int* cnt = (int*)alloc(4);
    size_t zr_bytes = (ws + off) - zr0;

    hipMemsetAsync(zr0, 0, zr_bytes, stream);
    detect_pcount_kernel<<<257, 256, 0, stream>>>((const uint32_t*)mask, flag, dst, pcount);
    wprep_embed_kernel<<<288 + (N_NODES * HDIM + 255) / 256, 256, 0, stream>>>(
        W1, W2, dW1, Wt1, Wt2, Wtd, x, mask, flag, tok, eW, eb, h);
    pscan_kernel<<<1, 256, 0, stream>>>(pcount, poff, pcursor, rowptr);
    partition_kernel<<<256, 256, 0, stream>>>(src, dst, pcursor, pairs);
    fill_part_kernel<<<NPART, 256, 0, stream>>>(pairs, poff, rowptr, col);

    for (int l = 0; l < L_LAYERS; ++l) {
        float* lstats = stats + (size_t)l * 2 * HDIM;
        agg_kernel<<<(N_NODES + 3) / 4, 256, 0, stream>>>(h, rowptr, col, z);
        fused_layer_kernel<<<(N_NODES + FL_RB - 1) / FL_RB, 512, 0, stream>>>(
            z, Wt1 + (size_t)l * HDIM * 2 * HDIM, b1 + (size_t)l * 2 * HDIM,
            Wt2 + (size_t)l * HDIM * 2 * HDIM, b2 + (size_t)l * HDIM, zin, lstats, N_NODES);
        bnapply_kernel<<<(N_NODES * HDIM / 8 + 255) / 256, 256, 0, stream>>>(
            zin, lstats, gm + l * HDIM, bt + l * HDIM, h);
    }

    const int DECB = (N_NODES + 63) / 64;
    dec_fused_kernel<<<DECB, 512, 0, stream>>>(h, Wtd, db1, dW2, db2, x, mask, flag, out + 1, lacc,
                                               cnt, out, DECB);
}

// Round 17
// 479.774 us; speedup vs baseline: 1.1840x; 1.1840x over previous
//
#include <hip/hip_runtime.h>
#include <cstdint>

#define N_NODES 50000
#define N_EDGES 1600000
#define HDIM 128
#define L_LAYERS 4
#define BN_EPS 1e-5f
#define NPART 196
#define PART_SHIFT 8
#define PB_CHUNK 6250  // N_EDGES / 256 exactly
#define FP_CAP 16384
#define FL_RB 128

typedef __attribute__((ext_vector_type(8))) short short8v;
typedef __attribute__((ext_vector_type(4))) float f32x4;

__device__ __forceinline__ unsigned short f2bf(float f) {
    uint32_t u = __builtin_bit_cast(uint32_t, f);
    u += 0x7fff + ((u >> 16) & 1);
    return (unsigned short)(u >> 16);
}
__device__ __forceinline__ float bf2f(unsigned short b) {
    return __builtin_bit_cast(float, (uint32_t)b << 16);
}

__device__ __forceinline__ int read_mask(const void* mask, int i, int bytelayout) {
    if (bytelayout) return ((const unsigned char*)mask)[i] != 0;
    return ((const int*)mask)[i] != 0;
}

// ---------------- K1: mask-layout detect (block 256) + per-partition count ----
__global__ __launch_bounds__(256) void detect_pcount_kernel(const uint32_t* __restrict__ mw,
                                                            int* __restrict__ flag,
                                                            const int* __restrict__ dst,
                                                            int* __restrict__ pcount) {
    if (blockIdx.x == 256) {
        __shared__ int f;
        if (threadIdx.x == 0) f = 0;
        __syncthreads();
        int found = 0;
        for (int i = threadIdx.x; i < 12500; i += 256)
            if (mw[i] > 1u) found = 1;
        if (found) f = 1;
        __syncthreads();
        if (threadIdx.x == 0) *flag = f;
        return;
    }
    __shared__ int hist[NPART];
    for (int i = threadIdx.x; i < NPART; i += 256) hist[i] = 0;
    __syncthreads();
    int lo = blockIdx.x * PB_CHUNK;
    for (int i = threadIdx.x; i < PB_CHUNK; i += 256)
        atomicAdd(&hist[dst[lo + i] >> PART_SHIFT], 1);
    __syncthreads();
    for (int i = threadIdx.x; i < NPART; i += 256)
        if (hist[i]) atomicAdd(&pcount[i], hist[i]);
}

// ---------------- K2: weight prep (blocks 0..287) + embed (rest) ----------------
__global__ __launch_bounds__(256) void wprep_embed_kernel(
    const float* __restrict__ W1, const float* __restrict__ W2, const float* __restrict__ dW1,
    unsigned short* __restrict__ Wt1, unsigned short* __restrict__ Wt2,
    unsigned short* __restrict__ Wtd, const float* __restrict__ x, const void* __restrict__ mask,
    const int* __restrict__ flag, const float* __restrict__ tok, const float* __restrict__ eW,
    const float* __restrict__ eb, unsigned short* __restrict__ h) {
    if (blockIdx.x < 288) {
        int seg = blockIdx.x / 32, bx = blockIdx.x & 31;
        const float* W;
        unsigned short* Wt;
        int K, nshift;
        if (seg < 4) {
            W = W1 + (size_t)seg * HDIM * 2 * HDIM;
            Wt = Wt1 + (size_t)seg * HDIM * 2 * HDIM;
            K = HDIM;
            nshift = 8;
        } else if (seg < 8) {
            int l = seg - 4;
            W = W2 + (size_t)l * 2 * HDIM * HDIM;
            Wt = Wt2 + (size_t)l * 2 * HDIM * HDIM;
            K = 2 * HDIM;
            nshift = 7;
        } else {
            W = dW1;
            Wt = Wtd;
            K = HDIM;
            nshift = 7;
        }
        int total = K << nshift;
        for (int idx = bx * 256 + (int)threadIdx.x; idx < total; idx += 32 * 256) {
            int k = idx >> nshift, n = idx & ((1 << nshift) - 1);
            Wt[(size_t)n * K + k] = f2bf(W[idx]);
        }
        return;
    }
    int idx = (blockIdx.x - 288) * 256 + threadIdx.x;
    if (idx >= N_NODES * HDIM) return;
    int i = idx >> 7, c = idx & 127;
    int fl = *flag;
    int m = read_mask(mask, i, fl);
    float x0 = m ? tok[0] : x[i * 3 + 0];
    float x1 = m ? tok[1] : x[i * 3 + 1];
    float x2 = m ? tok[2] : x[i * 3 + 2];
    h[idx] = f2bf(x0 * eW[c] + x1 * eW[HDIM + c] + x2 * eW[2 * HDIM + c] + eb[c]);
}

// ---------------- CSR build ----------------
__global__ __launch_bounds__(256) void pscan_kernel(const int* __restrict__ pcount,
                                                    int* __restrict__ poff,
                                                    int* __restrict__ pcursor,
                                                    int* __restrict__ rowptr) {
    __shared__ int sh[256];
    int t = threadIdx.x;
    int v = (t < NPART) ? pcount[t] : 0;
    sh[t] = v;
    __syncthreads();
    for (int o = 1; o < 256; o <<= 1) {
        int u = (t >= o) ? sh[t - o] : 0;
        __syncthreads();
        sh[t] += u;
        __syncthreads();
    }
    if (t < NPART) {
        int e = sh[t] - v;
        poff[t] = e;
        pcursor[t] = e;
    }
    if (t == NPART - 1) {
        poff[NPART] = sh[t];
        rowptr[N_NODES] = sh[t];
    }
}

__global__ __launch_bounds__(256) void partition_kernel(const int* __restrict__ src,
                                                        const int* __restrict__ dst,
                                                        int* __restrict__ pcursor,
                                                        uint32_t* __restrict__ pairs) {
    __shared__ int hist[NPART];
    __shared__ int off[NPART];
    int b = blockIdx.x, t = threadIdx.x;
    int lo = b * PB_CHUNK;
    for (int i = t; i < NPART; i += 256) hist[i] = 0;
    __syncthreads();
    for (int i = t; i < PB_CHUNK; i += 256) {
        int d = dst[lo + i];
        atomicAdd(&hist[d >> PART_SHIFT], 1);
    }
    __syncthreads();
    for (int i = t; i < NPART; i += 256) off[i] = atomicAdd(&pcursor[i], hist[i]);
    __syncthreads();
    for (int i = t; i < PB_CHUNK; i += 256) {
        int d = dst[lo + i];
        int s = src[lo + i];
        int pos = atomicAdd(&off[d >> PART_SHIFT], 1);
        pairs[pos] = (uint32_t)s | ((uint32_t)(d & 255) << 16);
    }
}

__global__ __launch_bounds__(256) void fill_part_kernel(const uint32_t* __restrict__ pairs,
                                                        const int* __restrict__ poff,
                                                        int* __restrict__ rowptr,
                                                        int* __restrict__ col) {
    __shared__ int colw[FP_CAP];
    __shared__ int lscan[256];
    __shared__ int lcur[256];
    int p = blockIdx.x, t = threadIdx.x;
    int base = p << PART_SHIFT;
    int nlocal = min(256, N_NODES - base);
    int pstart = poff[p], pend = poff[p + 1];
    int cnt = pend - pstart;
    lcur[t] = 0;
    __syncthreads();
    for (int e = pstart + t; e < pend; e += 256)
        atomicAdd(&lcur[(__builtin_nontemporal_load(&pairs[e]) >> 16) & 255], 1);
    __syncthreads();
    int v = lcur[t];
    lscan[t] = v;
    __syncthreads();
    for (int o = 1; o < 256; o <<= 1) {
        int u = (t >= o) ? lscan[t - o] : 0;
        __syncthreads();
        lscan[t] += u;
        __syncthreads();
    }
    int excl = lscan[t] - v;
    if (t < nlocal) rowptr[base + t] = pstart + excl;
    lcur[t] = excl;
    __syncthreads();
    if (cnt <= FP_CAP) {
        for (int e = pstart + t; e < pend; e += 256) {
            uint32_t pv = pairs[e];
            int pos = atomicAdd(&lcur[(pv >> 16) & 255], 1);
            colw[pos] = (int)(pv & 0xFFFFu);
        }
        __syncthreads();
        for (int e = t; e < cnt; e += 256) col[pstart + e] = colw[e];
    } else {
        for (int e = pstart + t; e < pend; e += 256) {
            uint32_t pv = pairs[e];
            int pos = atomicAdd(&lcur[(pv >> 16) & 255], 1);
            col[pstart + pos] = (int)(pv & 0xFFFFu);
        }
    }
}

// ---------------- aggregation (bf16 h): z[i] = h[i] + sum_{j} h[j] ----------------
#define AGG_LD(k)                                               \
    {                                                           \
        uint32_t uu = h32[(size_t)j##k * 64 + lane];            \
        ac##k.x += __builtin_bit_cast(float, uu << 16);         \
        ac##k.y += __builtin_bit_cast(float, uu & 0xffff0000u); \
    }
__global__ __launch_bounds__(256) void agg_kernel(const unsigned short* __restrict__ h,
                                                  const int* __restrict__ rowptr,
                                                  const int* __restrict__ col,
                                                  unsigned short* __restrict__ z) {
    int wid = threadIdx.x >> 6;
    int lane = threadIdx.x & 63;
    int i = __builtin_amdgcn_readfirstlane(blockIdx.x * 4 + wid);
    if (i >= N_NODES) return;
    int start = rowptr[i], end = rowptr[i + 1];
    const uint32_t* h32 = (const uint32_t*)h;
    uint32_t u = h32[(size_t)i * 64 + lane];
    float2 ac0 = make_float2(__builtin_bit_cast(float, u << 16),
                             __builtin_bit_cast(float, u & 0xffff0000u));
    float2 ac1 = make_float2(0.f, 0.f), ac2 = make_float2(0.f, 0.f), ac3 = make_float2(0.f, 0.f);
    float2 ac4 = make_float2(0.f, 0.f), ac5 = make_float2(0.f, 0.f), ac6 = make_float2(0.f, 0.f);
    float2 ac7 = make_float2(0.f, 0.f), ac8 = make_float2(0.f, 0.f), ac9 = make_float2(0.f, 0.f);
    float2 ac10 = make_float2(0.f, 0.f), ac11 = make_float2(0.f, 0.f),
           ac12 = make_float2(0.f, 0.f);
    float2 ac13 = make_float2(0.f, 0.f), ac14 = make_float2(0.f, 0.f),
           ac15 = make_float2(0.f, 0.f);
    int e = start;
    for (; e + 16 <= end; e += 16) {
        int j0 = col[e + 0], j1 = col[e + 1], j2 = col[e + 2], j3 = col[e + 3];
        int j4 = col[e + 4], j5 = col[e + 5], j6 = col[e + 6], j7 = col[e + 7];
        int j8 = col[e + 8], j9 = col[e + 9], j10 = col[e + 10], j11 = col[e + 11];
        int j12 = col[e + 12], j13 = col[e + 13], j14 = col[e + 14], j15 = col[e + 15];
        AGG_LD(0) AGG_LD(1) AGG_LD(2) AGG_LD(3) AGG_LD(4) AGG_LD(5) AGG_LD(6) AGG_LD(7)
        AGG_LD(8) AGG_LD(9) AGG_LD(10) AGG_LD(11) AGG_LD(12) AGG_LD(13) AGG_LD(14) AGG_LD(15)
    }
    for (; e + 4 <= end; e += 4) {
        int j0 = col[e + 0], j1 = col[e + 1], j2 = col[e + 2], j3 = col[e + 3];
        AGG_LD(0) AGG_LD(1) AGG_LD(2) AGG_LD(3)
    }
    for (; e < end; ++e) {
        int j0 = col[e];
        AGG_LD(0)
    }
    ac0.x += ((ac1.x + ac2.x) + (ac3.x + ac4.x)) + ((ac5.x + ac6.x) + (ac7.x + ac8.x)) +
             ((ac9.x + ac10.x) + (ac11.x + ac12.x)) + ((ac13.x + ac14.x) + ac15.x);
    ac0.y += ((ac1.y + ac2.y) + (ac3.y + ac4.y)) + ((ac5.y + ac6.y) + (ac7.y + ac8.y)) +
             ((ac9.y + ac10.y) + (ac11.y + ac12.y)) + ((ac13.y + ac14.y) + ac15.y);
    uint32_t o = (uint32_t)f2bf(ac0.x) | ((uint32_t)f2bf(ac0.y) << 16);
    ((uint32_t*)z)[(size_t)i * 64 + lane] = o;
}

// ---------------- fused layer (weight-stationary LDS); zin out = bf16 ----------------
__global__ __launch_bounds__(512) void fused_layer_kernel(
    const unsigned short* __restrict__ z, const unsigned short* __restrict__ Wt1,
    const float* __restrict__ b1, const unsigned short* __restrict__ Wt2,
    const float* __restrict__ b2, unsigned short* __restrict__ zin, float* __restrict__ stats,
    int M) {
    __shared__ unsigned short wbuf[256 * 136];
    __shared__ unsigned short z1l[FL_RB * 264];
    const int t = threadIdx.x;
    const int lane = t & 63;
    const int w = t >> 6;
    const int r = lane & 15, ks = lane >> 4;
    const int row0 = blockIdx.x * FL_RB + w * 16;
    const int arow = min(row0 + r, M - 1);
    for (int i = t; i < 256 * 16; i += 512) {
        int row = i >> 4, seg = i & 15;
        *(short8v*)&wbuf[row * 136 + seg * 8] = *(const short8v*)&Wt1[(size_t)row * 128 + seg * 8];
    }
    short8v a4[4];
#pragma unroll
    for (int kk = 0; kk < 4; ++kk)
        a4[kk] = *(const short8v*)&z[(size_t)arow * HDIM + kk * 32 + ks * 8];
    __syncthreads();
#pragma unroll
    for (int n = 0; n < 16; ++n) {
        f32x4 acc = (f32x4){0.f, 0.f, 0.f, 0.f};
#pragma unroll
        for (int kk = 0; kk < 4; ++kk) {
            short8v bf = *(const short8v*)&wbuf[(n * 16 + r) * 136 + kk * 32 + ks * 8];
            acc = __builtin_amdgcn_mfma_f32_16x16x32_bf16(a4[kk], bf, acc, 0, 0, 0);
        }
        float bv = b1[n * 16 + r];
#pragma unroll
        for (int i = 0; i < 4; ++i) {
            float o = fmaxf(acc[i] + bv, 0.f);
            z1l[(w * 16 + ks * 4 + i) * 264 + n * 16 + r] = f2bf(o);
        }
    }
    __syncthreads();
    for (int i = t; i < 128 * 32; i += 512) {
        int row = i >> 5, seg = i & 31;
        *(short8v*)&wbuf[row * 264 + seg * 8] = *(const short8v*)&Wt2[(size_t)row * 256 + seg * 8];
    }
    __syncthreads();
    f32x4 accb[8];
#pragma unroll
    for (int n = 0; n < 8; ++n) accb[n] = (f32x4){0.f, 0.f, 0.f, 0.f};
#pragma unroll
    for (int k0 = 0; k0 < 256; k0 += 32) {
        short8v a = *(const short8v*)&z1l[(w * 16 + r) * 264 + k0 + ks * 8];
#pragma unroll
        for (int n = 0; n < 8; ++n) {
            short8v bf = *(const short8v*)&wbuf[(n * 16 + r) * 264 + k0 + ks * 8];
            accb[n] = __builtin_amdgcn_mfma_f32_16x16x32_bf16(a, bf, accb[n], 0, 0, 0);
        }
    }
    __syncthreads();
    float* sred = (float*)wbuf;
#pragma unroll
    for (int n = 0; n < 8; ++n) {
        const int cc = n * 16 + r;
        const float bv = b2[cc];
        float s = 0.f, ss = 0.f;
#pragma unroll
        for (int i = 0; i < 4; ++i) {
            int row = row0 + ks * 4 + i;
            if (row < M) {
                float o = accb[n][i] + bv;
                unsigned short ur = f2bf(o);
                float orf = bf2f(ur);
                s += orf;
                ss += orf * orf;
                zin[(size_t)row * HDIM + cc] = ur;
            }
        }
        s += __shfl_xor(s, 16);
        s += __shfl_xor(s, 32);
        ss += __shfl_xor(ss, 16);
        ss += __shfl_xor(ss, 32);
        if (ks == 0) {
            sred[(w * 2 + 0) * HDIM + cc] = s;
            sred[(w * 2 + 1) * HDIM + cc] = ss;
        }
    }
    __syncthreads();
    if (t < HDIM) {
        float s = 0.f, ss = 0.f;
#pragma unroll
        for (int ww = 0; ww < 8; ++ww) {
            s += sred[(ww * 2 + 0) * HDIM + t];
            ss += sred[(ww * 2 + 1) * HDIM + t];
        }
        atomicAdd(&stats[t], s);
        atomicAdd(&stats[HDIM + t], ss);
    }
}

// ---------------- BN apply (bf16 in, bf16 out, 8 elems/thread) ----------------
__global__ __launch_bounds__(256) void bnapply_kernel(const unsigned short* __restrict__ zin,
                                                      const float* __restrict__ stats,
                                                      const float* __restrict__ gamma,
                                                      const float* __restrict__ beta,
                                                      unsigned short* __restrict__ h) {
    __shared__ float ssc[2 * HDIM];
    int t = threadIdx.x;
    if (t < HDIM) {
        float mean = stats[t] * (1.f / N_NODES);
        float var = stats[HDIM + t] * (1.f / N_NODES) - mean * mean;
        float rstd = rsqrtf(fmaxf(var, 0.f) + BN_EPS);
        float s = gamma[t] * rstd;
        ssc[t] = s;
        ssc[HDIM + t] = beta[t] - mean * s;
    }
    __syncthreads();
    int idx = blockIdx.x * 256 + t;
    if (idx >= N_NODES * HDIM / 8) return;
    short8v v = ((const short8v*)zin)[idx];
    int c = (idx * 8) & 127;
    short8v o;
#pragma unroll
    for (int j = 0; j < 8; ++j) {
        float val = fmaxf(bf2f((unsigned short)v[j]) * ssc[c + j] + ssc[HDIM + c + j], 0.f);
        o[j] = (short)f2bf(val);
    }
    ((short8v*)h)[idx] = o;
}

// ---------------- decoder stage 1: z1 = relu(h @ Wtd^T + db1), bf16 ----------------
__global__ __launch_bounds__(256) void mfma_gemm_kernel(const unsigned short* __restrict__ A,
                                                        const unsigned short* __restrict__ Wt,
                                                        const float* __restrict__ bias,
                                                        unsigned short* __restrict__ C, int M) {
    const int lane = threadIdx.x & 63;
    const int w = threadIdx.x >> 6;
    const int row0 = blockIdx.y * 64 + w * 16;
    const int col0 = blockIdx.x * 64;
    const int r = lane & 15;
    const int ks = lane >> 4;
    const int arow = min(row0 + r, M - 1);
    f32x4 acc[4];
#pragma unroll
    for (int n = 0; n < 4; ++n) acc[n] = (f32x4){0.f, 0.f, 0.f, 0.f};
#pragma unroll
    for (int k0 = 0; k0 < HDIM; k0 += 32) {
        short8v a = *(const short8v*)&A[(size_t)arow * HDIM + k0 + ks * 8];
#pragma unroll
        for (int n = 0; n < 4; ++n) {
            short8v b = *(const short8v*)&Wt[(size_t)(col0 + n * 16 + r) * HDIM + k0 + ks * 8];
            acc[n] = __builtin_amdgcn_mfma_f32_16x16x32_bf16(a, b, acc[n], 0, 0, 0);
        }
    }
#pragma unroll
    for (int n = 0; n < 4; ++n) {
        const int col = col0 + n * 16 + r;
        const float bv = bias[col];
#pragma unroll
        for (int i = 0; i < 4; ++i) {
            int row = row0 + ks * 4 + i;
            if (row < M) C[(size_t)row * HDIM + col] = f2bf(fmaxf(acc[n][i] + bv, 0.f));
        }
    }
}

// ---------------- decoder stage2 + loss + inline finalize ----------------
__global__ __launch_bounds__(256) void dec2_loss_kernel(
    const unsigned short* __restrict__ d1, const float* __restrict__ W2,
    const float* __restrict__ b2, const float* __restrict__ x, const void* __restrict__ mask,
    const int* __restrict__ flag, float* __restrict__ recon, float* __restrict__ acc,
    int* __restrict__ cnt, float* __restrict__ out_loss, int nblocks) {
    __shared__ float w2s[HDIM * 3];
    for (int t = threadIdx.x; t < HDIM * 3; t += 256) w2s[t] = W2[t];
    __syncthreads();
    int i = blockIdx.x * 256 + threadIdx.x;
    int fl = *flag;
    float lsum = 0.f, lcnt = 0.f;
    if (i < N_NODES) {
        float s0 = 0.f, s1 = 0.f, s2 = 0.f;
        const unsigned short* row = &d1[(size_t)i * HDIM];
#pragma unroll
        for (int k0 = 0; k0 < HDIM; k0 += 8) {
            short8v v = *(const short8v*)&row[k0];
#pragma unroll
            for (int q = 0; q < 8; ++q) {
                float a = bf2f((unsigned short)v[q]);
                s0 = fmaf(a, w2s[(k0 + q) * 3 + 0], s0);
                s1 = fmaf(a, w2s[(k0 + q) * 3 + 1], s1);
                s2 = fmaf(a, w2s[(k0 + q) * 3 + 2], s2);
            }
        }
        float r0 = s0 + b2[0], r1 = s1 + b2[1], r2 = s2 + b2[2];
        recon[(size_t)i * 3 + 0] = r0;
        recon[(size_t)i * 3 + 1] = r1;
        recon[(size_t)i * 3 + 2] = r2;
        if (read_mask(mask, i, fl)) {
            float rn = fmaxf(sqrtf(r0 * r0 + r1 * r1 + r2 * r2), 1e-12f);
            float x0 = x[i * 3 + 0], x1 = x[i * 3 + 1], x2 = x[i * 3 + 2];
            float xn = fmaxf(sqrtf(x0 * x0 + x1 * x1 + x2 * x2), 1e-12f);
            float cs = (r0 * x0 + r1 * x1 + r2 * x2) / (rn * xn);
            float d = 1.f - cs;
            lsum = d * d;
            lcnt = 1.f;
        }
    }
#pragma unroll
    for (int o = 32; o > 0; o >>= 1) {
        lsum += __shfl_xor(lsum, o);
        lcnt += __shfl_xor(lcnt, o);
    }
    if ((threadIdx.x & 63) == 0 && lcnt != 0.f) {
        atomicAdd(&acc[0], lsum);
        atomicAdd(&acc[1], lcnt);
    }
    __syncthreads();
    if (threadIdx.x == 0) {
        __threadfence();
        int done = atomicAdd(cnt, 1);
        if (done == nblocks - 1) {
            __threadfence();
            out_loss[0] = acc[0] / fmaxf(acc[1], 1.f);
        }
    }
}

// ---------------- launcher ----------------
extern "C" void kernel_launch(void* const* d_in, const int* in_sizes, int n_in, void* d_out,
                              int out_size, void* d_ws, size_t ws_size, hipStream_t stream) {
    const float* x = (const float*)d_in[0];
    const int* ei = (const int*)d_in[1];
    const int* src = ei;
    const int* dst = ei + N_EDGES;
    const void* mask = d_in[3];
    const float* tok = (const float*)d_in[4];
    const float* eW = (const float*)d_in[5];
    const float* eb = (const float*)d_in[6];
    const float* W1 = (const float*)d_in[7];
    const float* b1 = (const float*)d_in[8];
    const float* W2 = (const float*)d_in[9];
    const float* b2 = (const float*)d_in[10];
    const float* gm = (const float*)d_in[11];
    const float* bt = (const float*)d_in[12];
    const float* dW1 = (const float*)d_in[13];
    const float* db1 = (const float*)d_in[14];
    const float* dW2 = (const float*)d_in[15];
    const float* db2 = (const float*)d_in[16];
    float* out = (float*)d_out;

    char* ws = (char*)d_ws;
    size_t off = 0;
    auto alloc = [&](size_t bytes) -> void* {
        void* p = ws + off;
        off = (off + bytes + 255) & ~(size_t)255;
        return p;
    };
    unsigned short* h = (unsigned short*)alloc((size_t)N_NODES * HDIM * 2);
    unsigned short* z = (unsigned short*)alloc((size_t)N_NODES * HDIM * 2);
    unsigned short* zin = (unsigned short*)alloc((size_t)N_NODES * HDIM * 2);
    unsigned short* z1 = (unsigned short*)alloc((size_t)N_NODES * HDIM * 2);
    unsigned short* Wt1 = (unsigned short*)alloc((size_t)L_LAYERS * HDIM * 2 * HDIM * 2);
    unsigned short* Wt2 = (unsigned short*)alloc((size_t)L_LAYERS * HDIM * 2 * HDIM * 2);
    unsigned short* Wtd = (unsigned short*)alloc((size_t)HDIM * HDIM * 2);
    int* rowptr = (int*)alloc((size_t)(N_NODES + 1) * 4);
    int* col = (int*)alloc((size_t)N_EDGES * 4);
    uint32_t* pairs = (uint32_t*)alloc((size_t)N_EDGES * 4);
    int* poff = (int*)alloc((size_t)(NPART + 1) * 4);
    int* pcursor = (int*)alloc((size_t)NPART * 4);
    int* flag = (int*)alloc(4);
    // zero-region (single memset): pcount, stats, lacc, cnt
    char* zr0 = ws + off;
    int* pcount = (int*)alloc((size_t)NPART * 4);
    float* stats = (float*)alloc((size_t)L_LAYERS * 2 * HDIM * 4);
    float* lacc = (float*)alloc(8);
    int* cnt = (int*)alloc(4);
    size_t zr_bytes = (ws + off) - zr0;

    hipMemsetAsync(zr0, 0, zr_bytes, stream);
    detect_pcount_kernel<<<257, 256, 0, stream>>>((const uint32_t*)mask, flag, dst, pcount);
    wprep_embed_kernel<<<288 + (N_NODES * HDIM + 255) / 256, 256, 0, stream>>>(
        W1, W2, dW1, Wt1, Wt2, Wtd, x, mask, flag, tok, eW, eb, h);
    pscan_kernel<<<1, 256, 0, stream>>>(pcount, poff, pcursor, rowptr);
    partition_kernel<<<256, 256, 0, stream>>>(src, dst, pcursor, pairs);
    fill_part_kernel<<<NPART, 256, 0, stream>>>(pairs, poff, rowptr, col);

    for (int l = 0; l < L_LAYERS; ++l) {
        float* lstats = stats + (size_t)l * 2 * HDIM;
        agg_kernel<<<(N_NODES + 3) / 4, 256, 0, stream>>>(h, rowptr, col, z);
        fused_layer_kernel<<<(N_NODES + FL_RB - 1) / FL_RB, 512, 0, stream>>>(
            z, Wt1 + (size_t)l * HDIM * 2 * HDIM, b1 + (size_t)l * 2 * HDIM,
            Wt2 + (size_t)l * HDIM * 2 * HDIM, b2 + (size_t)l * HDIM, zin, lstats, N_NODES);
        bnapply_kernel<<<(N_NODES * HDIM / 8 + 255) / 256, 256, 0, stream>>>(
            zin, lstats, gm + l * HDIM, bt + l * HDIM, h);
    }

    mfma_gemm_kernel<<<dim3(2, 782), 256, 0, stream>>>(h, Wtd, db1, z1, N_NODES);
    const int D2B = (N_NODES + 255) / 256;
    dec2_loss_kernel<<<D2B, 256, 0, stream>>>(z1, dW2, db2, x, mask, flag, out + 1, lacc, cnt, out,
                                              D2B);
}